// Round 11
// baseline (368.272 us; speedup 1.0000x reference)
//
#include <hip/hip_runtime.h>
#include <hip/hip_bf16.h>

#define N_NODES 50000
#define E0_EDGES 800000
#define E_TOTAL 850000   // E0 + self loops
#define NEG_SLOPE 0.2f
#define BN_EPS 1e-5f
#define CAP 64           // per-node LDS edge cache; mean deg 17, P(deg>64)~0 (fallback correct)

typedef __attribute__((ext_vector_type(8))) short bf16x8;
typedef __attribute__((ext_vector_type(4))) float f32x4;

__device__ __forceinline__ float lrelu(float x) { return x > 0.f ? x : NEG_SLOPE * x; }

__device__ __forceinline__ ushort f2bf(float x) {
    __hip_bfloat16 b = __float2bfloat16(x);   // RNE
    return *reinterpret_cast<ushort*>(&b);
}
__device__ __forceinline__ float bf2f(ushort u) {
    return __uint_as_float(((unsigned int)u) << 16);
}

// ---------------- fused prep: zero + W1/W2 transpose + mw1 transpose + x->bf16 ----------------
#define PREP_Z 196            // zero blocks
#define PREP_W 256            // weight-transpose blocks (1 col each)
#define PREP_F 3125           // featprep blocks (N*64/1024)
__global__ void k_prep(int* __restrict__ deg, float* __restrict__ gsum, float* __restrict__ gsumsq,
                       const float* __restrict__ W1, const float* __restrict__ W2,
                       ushort* __restrict__ WbfT1, ushort* __restrict__ WbfT2,
                       const float* __restrict__ mw1, ushort* __restrict__ mwT,
                       const float* __restrict__ x, ushort* __restrict__ xbf) {
    int b = blockIdx.x;
    int tid = threadIdx.x;
    if (b < PREP_Z) {
        int i = b * 256 + tid;
        if (i < N_NODES) deg[i] = 0;
        if (i < 200) { gsum[i] = 0.f; gsumsq[i] = 0.f; }
    } else if (b < PREP_Z + PREP_W) {
        int c = b - PREP_Z;
        if (tid < 64)        WbfT1[c * 64 + tid] = f2bf(W1[tid * 256 + c]);
        else if (tid < 128)  WbfT2[c * 64 + (tid - 64)] = f2bf(W2[(tid - 64) * 256 + c]);
        else if (tid < 192 && c < 200) mwT[c * 64 + (tid - 128)] = f2bf(mw1[(tid - 128) * 200 + c]);
    } else {
        int i = ((b - PREP_Z - PREP_W) * 256 + tid) * 4;
        float4 v = *(const float4*)&x[i];
        ushort4 o;
        o.x = f2bf(v.x); o.y = f2bf(v.y); o.z = f2bf(v.z); o.w = f2bf(v.w);
        *(ushort4*)&xbf[i] = o;
    }
}

// ---------------- CSR build ----------------
// rank trick: atomic return value IS the edge's slot in its dst row (max in-deg ~50 -> ushort safe).
__global__ void k_count(const int* __restrict__ ei, int* __restrict__ deg, ushort* __restrict__ rank) {
    int e = blockIdx.x * 256 + threadIdx.x;
    if (e >= E_TOTAL) return;
    int dst = (e < E0_EDGES) ? ei[E0_EDGES + e] : (e - E0_EDGES);
    rank[e] = (ushort)atomicAdd(&deg[dst], 1);
}

__global__ void k_scanA(const int* __restrict__ deg, int* __restrict__ rowptr, int* __restrict__ bsum) {
    __shared__ int s[256];
    int i = blockIdx.x * 256 + threadIdx.x;
    int v = (i < N_NODES) ? deg[i] : 0;
    s[threadIdx.x] = v;
    __syncthreads();
    for (int off = 1; off < 256; off <<= 1) {
        int t = (threadIdx.x >= off) ? s[threadIdx.x - off] : 0;
        __syncthreads();
        s[threadIdx.x] += t;
        __syncthreads();
    }
    if (i < N_NODES) rowptr[i] = s[threadIdx.x];            // inclusive within block
    if (threadIdx.x == 255) bsum[blockIdx.x] = s[255];
}

// scanC with inline exclusive block-offset: each block reduces bsum[0..blockIdx-1] itself.
__global__ void k_scanC(const int* __restrict__ deg, int* __restrict__ rowptr,
                        const int* __restrict__ bsum, int nb) {
    __shared__ int s[256];
    int tid = threadIdx.x;
    s[tid] = (tid < nb && tid < blockIdx.x) ? bsum[tid] : 0;
    __syncthreads();
    for (int off = 128; off; off >>= 1) {
        if (tid < off) s[tid] += s[tid + off];
        __syncthreads();
    }
    int blockoff = s[0];
    int i = blockIdx.x * 256 + tid;
    if (i >= N_NODES) return;
    rowptr[i] = blockoff + rowptr[i] - deg[i];              // exclusive global
    if (i == N_NODES - 1) rowptr[N_NODES] = E_TOTAL;
}

// ---------------- merged: atomic-free CSR fill  +  layer-1 feature GEMM ----------------
#define FG_FILL 3321          // NB_E blocks for fill
#define FG_GEMM 3125          // N/16 blocks for gemm
__device__ __forceinline__ void gemm_feat_body(int bid, const ushort* __restrict__ x,
                                               const ushort* __restrict__ WbfT,
                                               const float* __restrict__ al, const float* __restrict__ ar,
                                               ushort* __restrict__ featB,
                                               float* __restrict__ el, float* __restrict__ er,
                                               float (*fs)[256]) {
    int tid = threadIdx.x;
    int wave = tid >> 6, lane = tid & 63;
    int row0 = bid * 16;
    int lr = lane & 15;      // A row / B col within tile
    int q = lane >> 4;       // k-chunk (8 k's per chunk)

    // A fragments: two 16B vector loads (all 4 waves same 16 rows; L1-hit)
    const ushort* ap = x + (size_t)(row0 + lr) * 64 + q * 8;
    bf16x8 a0 = *reinterpret_cast<const bf16x8*>(ap);
    bf16x8 a1 = *reinterpret_cast<const bf16x8*>(ap + 32);

#pragma unroll
    for (int t = 0; t < 4; t++) {
        int ct = wave * 4 + t;
        const ushort* wrow = WbfT + (size_t)(ct * 16 + lr) * 64 + q * 8;
        bf16x8 b0 = *reinterpret_cast<const bf16x8*>(wrow);        // k 0..31 chunk
        bf16x8 b1 = *reinterpret_cast<const bf16x8*>(wrow + 32);   // k 32..63 chunk
        f32x4 acc = {0.f, 0.f, 0.f, 0.f};
        acc = __builtin_amdgcn_mfma_f32_16x16x32_bf16(a0, b0, acc, 0, 0, 0);
        acc = __builtin_amdgcn_mfma_f32_16x16x32_bf16(a1, b1, acc, 0, 0, 0);
#pragma unroll
        for (int i = 0; i < 4; i++)
            fs[q * 4 + i][ct * 16 + lr] = acc[i];
    }
    __syncthreads();

    // el/er: task (r,h) over 4 lanes, each lane sums 16 dims
    {
        int r = tid >> 4;
        int rem = tid & 15;
        int h = rem >> 2;
        int l = rem & 3;
        int d0 = l * 16;
        float vl = 0.f, vr = 0.f;
#pragma unroll
        for (int j = 0; j < 16; j += 4) {
            float4 f = *(const float4*)&fs[r][h * 64 + d0 + j];
            float4 a = *(const float4*)&al[h * 64 + d0 + j];
            float4 b = *(const float4*)&ar[h * 64 + d0 + j];
            vl += f.x * a.x + f.y * a.y + f.z * a.z + f.w * a.w;
            vr += f.x * b.x + f.y * b.y + f.z * b.z + f.w * b.w;
        }
        vl += __shfl_xor(vl, 1, 64); vl += __shfl_xor(vl, 2, 64);
        vr += __shfl_xor(vr, 1, 64); vr += __shfl_xor(vr, 2, 64);
        if (l == 0) {
            el[(row0 + r) * 4 + h] = vl;
            er[(row0 + r) * 4 + h] = vr;
        }
    }

    // featB[i*256 + j], j=d*4+h -> source col = (j&3)*64 + (j>>2)
    int c = tid;
    int srcc = ((c & 3) << 6) + (c >> 2);
#pragma unroll
    for (int r = 0; r < 16; r++)
        featB[(size_t)(row0 + r) * 256 + c] = f2bf(fs[r][srcc]);
}

__global__ void k_fill_gemm(const int* __restrict__ ei, const int* __restrict__ rowptr,
                            const ushort* __restrict__ rank, ushort* __restrict__ colidx,
                            const ushort* __restrict__ x, const ushort* __restrict__ WbfT,
                            const float* __restrict__ al, const float* __restrict__ ar,
                            ushort* __restrict__ featB, float* __restrict__ el, float* __restrict__ er) {
    __shared__ float fs[16][256];
    if (blockIdx.x < FG_FILL) {
        int e = blockIdx.x * 256 + threadIdx.x;
        if (e >= E_TOTAL) return;
        int src, dst;
        if (e < E0_EDGES) { src = ei[e]; dst = ei[E0_EDGES + e]; }
        else { src = e - E0_EDGES; dst = src; }
        colidx[rowptr[dst] + rank[e]] = (ushort)src;
        return;
    }
    gemm_feat_body(blockIdx.x - FG_FILL, x, WbfT, al, ar, featB, el, er, fs);
}

__global__ void k_gemm_feat(const ushort* __restrict__ x, const ushort* __restrict__ WbfT,
                            const float* __restrict__ al, const float* __restrict__ ar,
                            ushort* __restrict__ featB, float* __restrict__ el, float* __restrict__ er) {
    __shared__ float fs[16][256];
    gemm_feat_body(blockIdx.x, x, WbfT, al, ar, featB, el, er, fs);
}

// ---------------- merged edge-softmax + aggregation (R7 proven form) ----------------
// Max pass removed (softmax shift-invariance; |logit| <= ~1 so no overflow).
__global__ void k_gat(const float4* __restrict__ el4, const float4* __restrict__ er4,
                      const int* __restrict__ rowptr, const ushort* __restrict__ colidx,
                      const ushort* __restrict__ featB, const float* __restrict__ bias,
                      ushort* __restrict__ hout) {
    __shared__ float4 sE[4][CAP];
    __shared__ int    sSrc[4][CAP];
    int tid = threadIdx.x;
    int w = tid >> 6, lane = tid & 63;
    int row = blockIdx.x * 4 + w;
    int start = rowptr[row];
    int deg = rowptr[row + 1] - start;
    int cached = min(deg, CAP);
    float4 erow = er4[row];

    // phase 1: logits -> exp -> LDS cache + denom
    float4 sm = make_float4(0.f, 0.f, 0.f, 0.f);
    for (int idx = lane; idx < cached; idx += 64) {
        int src = colidx[start + idx];
        float4 e = el4[src];
        float4 ex;
        ex.x = __expf(lrelu(e.x + erow.x));
        ex.y = __expf(lrelu(e.y + erow.y));
        ex.z = __expf(lrelu(e.z + erow.z));
        ex.w = __expf(lrelu(e.w + erow.w));
        sE[w][idx] = ex; sSrc[w][idx] = src;
        sm.x += ex.x; sm.y += ex.y; sm.z += ex.z; sm.w += ex.w;
    }
    for (int idx = CAP + lane; idx < deg; idx += 64) {      // rare tail
        int src = colidx[start + idx];
        float4 e = el4[src];
        sm.x += __expf(lrelu(e.x + erow.x));
        sm.y += __expf(lrelu(e.y + erow.y));
        sm.z += __expf(lrelu(e.z + erow.z));
        sm.w += __expf(lrelu(e.w + erow.w));
    }
#pragma unroll
    for (int off = 32; off; off >>= 1) {
        sm.x += __shfl_xor(sm.x, off, 64);
        sm.y += __shfl_xor(sm.y, off, 64);
        sm.z += __shfl_xor(sm.z, off, 64);
        sm.w += __shfl_xor(sm.w, off, 64);
    }
    float4 dr;
    dr.x = 1.f / sm.x; dr.y = 1.f / sm.y; dr.z = 1.f / sm.z; dr.w = 1.f / sm.w;

    // phase 2: serial edge loop, lane = dim; unroll 4 (VGPR/occ sweet spot)
    const ushort4* featB4 = (const ushort4*)featB;
    float4 acc = make_float4(0.f, 0.f, 0.f, 0.f);
#pragma unroll 4
    for (int s = 0; s < cached; s++) {
        float4 ex = sE[w][s];
        int src = sSrc[w][s];
        ushort4 f = featB4[(size_t)src * 64 + lane];
        acc.x = fmaf(bf2f(f.x), ex.x, acc.x);
        acc.y = fmaf(bf2f(f.y), ex.y, acc.y);
        acc.z = fmaf(bf2f(f.z), ex.z, acc.z);
        acc.w = fmaf(bf2f(f.w), ex.w, acc.w);
    }
    for (int s = CAP; s < deg; s++) {                       // rare tail
        int src = colidx[start + s];
        float4 e = el4[src];
        float4 ex;
        ex.x = __expf(lrelu(e.x + erow.x));
        ex.y = __expf(lrelu(e.y + erow.y));
        ex.z = __expf(lrelu(e.z + erow.z));
        ex.w = __expf(lrelu(e.w + erow.w));
        ushort4 f = featB4[(size_t)src * 64 + lane];
        acc.x = fmaf(bf2f(f.x), ex.x, acc.x);
        acc.y = fmaf(bf2f(f.y), ex.y, acc.y);
        acc.z = fmaf(bf2f(f.z), ex.z, acc.z);
        acc.w = fmaf(bf2f(f.w), ex.w, acc.w);
    }
    float o = fmaxf(fmaf(acc.x, dr.x, bias[lane]), 0.f)
            + fmaxf(fmaf(acc.y, dr.y, bias[64 + lane]), 0.f)
            + fmaxf(fmaf(acc.z, dr.z, bias[128 + lane]), 0.f)
            + fmaxf(fmaf(acc.w, dr.w, bias[192 + lane]), 0.f);
    hout[(size_t)row * 64 + lane] = f2bf(o * 0.25f);
}

// ---------------- MLP layer-1 via MFMA: z = relu(h@mw1+mb1), fused BN stats ----------------
// 32 rows/block (8 waves: waves 0-3 rows 0-15, waves 4-7 rows 16-31), 13 col-tiles of 16
// (tile 12 masked at col>=200). Stats: shfl-reduce over q, LDS-combine row-halves,
// 1 atomic pair per col per block.
#define MLP_TILES 13
__global__ __launch_bounds__(512) void k_mlp1_mfma(const ushort* __restrict__ h, const ushort* __restrict__ mwT,
                                                   const float* __restrict__ mb1, ushort* __restrict__ z,
                                                   float* __restrict__ gsum, float* __restrict__ gsumsq) {
    __shared__ float sS[MLP_TILES * 16], sS2[MLP_TILES * 16];
    int tid = threadIdx.x;
    int wave = tid >> 6, lane = tid & 63;
    int lr = lane & 15, q = lane >> 4;
    int half = wave >> 2;                       // row half (0: rows 0-15, 1: rows 16-31)
    int tidx = wave & 3;
    int rowbase = blockIdx.x * 32 + half * 16;

    // A fragments: rows rowbase+lr (last block over-reads past N; masked below)
    const ushort* ap = h + (size_t)(rowbase + lr) * 64 + q * 8;
    bf16x8 a0 = *reinterpret_cast<const bf16x8*>(ap);
    bf16x8 a1 = *reinterpret_cast<const bf16x8*>(ap + 32);

    for (int ct = tidx; ct < MLP_TILES; ct += 4) {
        const ushort* wrow = mwT + (size_t)(ct * 16 + lr) * 64 + q * 8;
        bf16x8 b0 = *reinterpret_cast<const bf16x8*>(wrow);
        bf16x8 b1 = *reinterpret_cast<const bf16x8*>(wrow + 32);
        f32x4 acc = {0.f, 0.f, 0.f, 0.f};
        acc = __builtin_amdgcn_mfma_f32_16x16x32_bf16(a0, b0, acc, 0, 0, 0);
        acc = __builtin_amdgcn_mfma_f32_16x16x32_bf16(a1, b1, acc, 0, 0, 0);

        int col = ct * 16 + lr;
        bool colok = (col < 200);
        float bv = colok ? mb1[col] : 0.f;
        float s = 0.f, s2 = 0.f;
#pragma unroll
        for (int i = 0; i < 4; i++) {
            int row = rowbase + q * 4 + i;
            float v = fmaxf(acc[i] + bv, 0.f);
            if (colok && row < N_NODES) {
                z[(size_t)row * 200 + col] = f2bf(v);
                s += v;
                s2 = fmaf(v, v, s2);
            }
        }
        // reduce the 16-row partials over q (lanes q*16+lr)
        s  += __shfl_xor(s, 16, 64);  s  += __shfl_xor(s, 32, 64);
        s2 += __shfl_xor(s2, 16, 64); s2 += __shfl_xor(s2, 32, 64);
        if (q == 0) {
            if (half == 0) { sS[ct * 16 + lr] = s; sS2[ct * 16 + lr] = s2; }
        }
    }
    __syncthreads();
    // row-half 1 combines with half 0's LDS partials and issues the atomics
    if (half == 1 && q == 0) {
        for (int ct = tidx; ct < MLP_TILES; ct += 4) {
            int col = ct * 16 + lr;
            if (col < 200) {
                // recompute this wave's (s,s2)? no — pass via registers: redo loop structure instead
            }
        }
    }
}

// NOTE: the combine above is replaced by a simpler scheme below (kept single definition).
// To avoid cross-loop register passing complexity, half-1 waves do their own atomics too.
__global__ __launch_bounds__(512) void k_mlp1_mfma2(const ushort* __restrict__ h, const ushort* __restrict__ mwT,
                                                    const float* __restrict__ mb1, ushort* __restrict__ z,
                                                    float* __restrict__ gsum, float* __restrict__ gsumsq) {
    int tid = threadIdx.x;
    int wave = tid >> 6, lane = tid & 63;
    int lr = lane & 15, q = lane >> 4;
    int half = wave >> 2;
    int tidx = wave & 3;
    int rowbase = blockIdx.x * 32 + half * 16;

    const ushort* ap = h + (size_t)(rowbase + lr) * 64 + q * 8;
    bf16x8 a0 = *reinterpret_cast<const bf16x8*>(ap);
    bf16x8 a1 = *reinterpret_cast<const bf16x8*>(ap + 32);

    for (int ct = tidx; ct < MLP_TILES; ct += 4) {
        const ushort* wrow = mwT + (size_t)(ct * 16 + lr) * 64 + q * 8;
        bf16x8 b0 = *reinterpret_cast<const bf16x8*>(wrow);
        bf16x8 b1 = *reinterpret_cast<const bf16x8*>(wrow + 32);
        f32x4 acc = {0.f, 0.f, 0.f, 0.f};
        acc = __builtin_amdgcn_mfma_f32_16x16x32_bf16(a0, b0, acc, 0, 0, 0);
        acc = __builtin_amdgcn_mfma_f32_16x16x32_bf16(a1, b1, acc, 0, 0, 0);

        int col = ct * 16 + lr;
        bool colok = (col < 200);
        float bv = colok ? mb1[col] : 0.f;
        float s = 0.f, s2 = 0.f;
#pragma unroll
        for (int i = 0; i < 4; i++) {
            int row = rowbase + q * 4 + i;
            float v = fmaxf(acc[i] + bv, 0.f);
            if (colok && row < N_NODES) {
                z[(size_t)row * 200 + col] = f2bf(v);
                s += v;
                s2 = fmaf(v, v, s2);
            }
        }
        s  += __shfl_xor(s, 16, 64);  s  += __shfl_xor(s, 32, 64);
        s2 += __shfl_xor(s2, 16, 64); s2 += __shfl_xor(s2, 32, 64);
        if (q == 0 && colok) {
            atomicAdd(&gsum[col], s);
            atomicAdd(&gsumsq[col], s2);
        }
    }
}

// ---------------- final linear with BN folded in-kernel (bnprep eliminated) ----------------
__global__ void k_final(const ushort* __restrict__ z, const float* __restrict__ gsum,
                        const float* __restrict__ gsumsq, const float* __restrict__ bn_g,
                        const float* __restrict__ bn_b, const float* __restrict__ mw2,
                        const float* __restrict__ mb2, float* __restrict__ out) {
    int tid = threadIdx.x;
    int row = blockIdx.x * 4 + (tid >> 6);
    int lane = tid & 63;
    const float invN = 1.f / (float)N_NODES;
    float a0 = 0.f, a1 = 0.f;
    for (int c = lane; c < 200; c += 64) {
        float mu = gsum[c] * invN;
        float var = gsumsq[c] * invN - mu * mu;
        float alpha = bn_g[c] * rsqrtf(var + BN_EPS);
        float beta = bn_b[c] - mu * alpha;
        float zn = fmaf(alpha, bf2f(z[(size_t)row * 200 + c]), beta);
        a0 = fmaf(zn, mw2[c * 2], a0);
        a1 = fmaf(zn, mw2[c * 2 + 1], a1);
    }
#pragma unroll
    for (int off = 32; off; off >>= 1) {
        a0 += __shfl_xor(a0, off, 64);
        a1 += __shfl_xor(a1, off, 64);
    }
    if (lane == 0) {
        out[row * 2] = a0 + mb2[0];
        out[row * 2 + 1] = a1 + mb2[1];
    }
}

extern "C" void kernel_launch(void* const* d_in, const int* in_sizes, int n_in,
                              void* d_out, int out_size, void* d_ws, size_t ws_size,
                              hipStream_t stream) {
    const float* features = (const float*)d_in[0];
    const int*   ei       = (const int*)d_in[1];
    const float* W1  = (const float*)d_in[2];
    const float* al1 = (const float*)d_in[3];
    const float* ar1 = (const float*)d_in[4];
    const float* b1  = (const float*)d_in[5];
    const float* W2  = (const float*)d_in[6];
    const float* al2 = (const float*)d_in[7];
    const float* ar2 = (const float*)d_in[8];
    const float* b2  = (const float*)d_in[9];
    const float* mw1 = (const float*)d_in[10];
    const float* mb1 = (const float*)d_in[11];
    const float* bng = (const float*)d_in[12];
    const float* bnb = (const float*)d_in[13];
    const float* mw2 = (const float*)d_in[14];
    const float* mb2 = (const float*)d_in[15];
    float* out = (float*)d_out;

    // ---- workspace layout ----
    char* base = (char*)d_ws;
    size_t off = 0;
    auto alloc = [&](size_t bytes) -> char* {
        char* p = base + off;
        off = (off + bytes + 255) & ~(size_t)255;
        return p;
    };
    int*    deg    = (int*)alloc(N_NODES * 4);
    int*    rowptr = (int*)alloc((N_NODES + 1) * 4);
    ushort* rank   = (ushort*)alloc(E_TOTAL * 2);
    int*    bsum   = (int*)alloc(256 * 4);
    ushort* colidx = (ushort*)alloc(E_TOTAL * 2);
    ushort* featB  = (ushort*)alloc((size_t)N_NODES * 256 * 2);
    float*  el     = (float*)alloc((size_t)N_NODES * 4 * 4);
    float*  er     = (float*)alloc((size_t)N_NODES * 4 * 4);
    ushort* xbf    = (ushort*)alloc((size_t)N_NODES * 64 * 2);
    ushort* h1     = (ushort*)alloc((size_t)N_NODES * 64 * 2);
    ushort* h2     = (ushort*)alloc((size_t)N_NODES * 64 * 2);
    ushort* z      = (ushort*)alloc((size_t)N_NODES * 200 * 2);
    float*  gsum   = (float*)alloc(256 * 4);
    float*  gsumsq = (float*)alloc(256 * 4);
    ushort* WbfT1  = (ushort*)alloc(256 * 64 * 2);
    ushort* WbfT2  = (ushort*)alloc(256 * 64 * 2);
    ushort* mwT    = (ushort*)alloc(208 * 64 * 2);
    (void)ws_size; (void)in_sizes; (void)n_in; (void)out_size;

    const int NB_N = (N_NODES + 255) / 256;   // 196
    const int NB_E = (E_TOTAL + 255) / 256;   // 3321

    // prep + CSR build
    k_prep<<<PREP_Z + PREP_W + PREP_F, 256, 0, stream>>>(deg, gsum, gsumsq,
                                                         W1, W2, WbfT1, WbfT2,
                                                         mw1, mwT, features, xbf);
    k_count<<<NB_E, 256, 0, stream>>>(ei, deg, rank);
    k_scanA<<<NB_N, 256, 0, stream>>>(deg, rowptr, bsum);
    k_scanC<<<NB_N, 256, 0, stream>>>(deg, rowptr, bsum, NB_N);

    // GAT layer 1 (fill + gemm fused)
    k_fill_gemm<<<FG_FILL + FG_GEMM, 256, 0, stream>>>(ei, rowptr, rank, colidx,
                                                       xbf, WbfT1, al1, ar1, featB, el, er);
    k_gat<<<N_NODES / 4, 256, 0, stream>>>((const float4*)el, (const float4*)er, rowptr, colidx, featB, b1, h1);

    // GAT layer 2
    k_gemm_feat<<<N_NODES / 16, 256, 0, stream>>>(h1, WbfT2, al2, ar2, featB, el, er);
    k_gat<<<N_NODES / 4, 256, 0, stream>>>((const float4*)el, (const float4*)er, rowptr, colidx, featB, b2, h2);

    // MLP head (MFMA GEMM + fused stats; BN folded into final)
    k_mlp1_mfma2<<<(N_NODES + 31) / 32, 512, 0, stream>>>(h2, mwT, mb1, z, gsum, gsumsq);
    k_final<<<N_NODES / 4, 256, 0, stream>>>(z, gsum, gsumsq, bng, bnb, mw2, mb2, out);
}

// Round 12
// 281.761 us; speedup vs baseline: 1.3070x; 1.3070x over previous
//
#include <hip/hip_runtime.h>
#include <hip/hip_bf16.h>

#define N_NODES 50000
#define E0_EDGES 800000
#define E_TOTAL 850000   // E0 + self loops
#define NEG_SLOPE 0.2f
#define BN_EPS 1e-5f
#define CAP 64           // per-node LDS edge cache; mean deg 17, P(deg>64)~0 (fallback correct)

typedef __attribute__((ext_vector_type(8))) short bf16x8;
typedef __attribute__((ext_vector_type(4))) float f32x4;

__device__ __forceinline__ float lrelu(float x) { return x > 0.f ? x : NEG_SLOPE * x; }

__device__ __forceinline__ ushort f2bf(float x) {
    __hip_bfloat16 b = __float2bfloat16(x);   // RNE
    return *reinterpret_cast<ushort*>(&b);
}
__device__ __forceinline__ float bf2f(ushort u) {
    return __uint_as_float(((unsigned int)u) << 16);
}

// ---------------- fused prep: zero + W1/W2 transpose + mw1 transpose + x->bf16 ----------------
#define PREP_Z 196            // zero blocks
#define PREP_W 256            // weight-transpose blocks (1 col each)
#define PREP_F 3125           // featprep blocks (N*64/1024)
__global__ void k_prep(int* __restrict__ deg, float* __restrict__ gsum, float* __restrict__ gsumsq,
                       const float* __restrict__ W1, const float* __restrict__ W2,
                       ushort* __restrict__ WbfT1, ushort* __restrict__ WbfT2,
                       const float* __restrict__ mw1, ushort* __restrict__ mwT,
                       const float* __restrict__ x, ushort* __restrict__ xbf) {
    int b = blockIdx.x;
    int tid = threadIdx.x;
    if (b < PREP_Z) {
        int i = b * 256 + tid;
        if (i < N_NODES) deg[i] = 0;
        if (i < 200) { gsum[i] = 0.f; gsumsq[i] = 0.f; }
    } else if (b < PREP_Z + PREP_W) {
        int c = b - PREP_Z;
        if (tid < 64)        WbfT1[c * 64 + tid] = f2bf(W1[tid * 256 + c]);
        else if (tid < 128)  WbfT2[c * 64 + (tid - 64)] = f2bf(W2[(tid - 64) * 256 + c]);
        else if (tid < 192 && c < 200) mwT[c * 64 + (tid - 128)] = f2bf(mw1[(tid - 128) * 200 + c]);
    } else {
        int i = ((b - PREP_Z - PREP_W) * 256 + tid) * 4;
        float4 v = *(const float4*)&x[i];
        ushort4 o;
        o.x = f2bf(v.x); o.y = f2bf(v.y); o.z = f2bf(v.z); o.w = f2bf(v.w);
        *(ushort4*)&xbf[i] = o;
    }
}

// ---------------- CSR build ----------------
// rank trick: atomic return value IS the edge's slot in its dst row (max in-deg ~50 -> ushort safe).
__global__ void k_count(const int* __restrict__ ei, int* __restrict__ deg, ushort* __restrict__ rank) {
    int e = blockIdx.x * 256 + threadIdx.x;
    if (e >= E_TOTAL) return;
    int dst = (e < E0_EDGES) ? ei[E0_EDGES + e] : (e - E0_EDGES);
    rank[e] = (ushort)atomicAdd(&deg[dst], 1);
}

__global__ void k_scanA(const int* __restrict__ deg, int* __restrict__ rowptr, int* __restrict__ bsum) {
    __shared__ int s[256];
    int i = blockIdx.x * 256 + threadIdx.x;
    int v = (i < N_NODES) ? deg[i] : 0;
    s[threadIdx.x] = v;
    __syncthreads();
    for (int off = 1; off < 256; off <<= 1) {
        int t = (threadIdx.x >= off) ? s[threadIdx.x - off] : 0;
        __syncthreads();
        s[threadIdx.x] += t;
        __syncthreads();
    }
    if (i < N_NODES) rowptr[i] = s[threadIdx.x];            // inclusive within block
    if (threadIdx.x == 255) bsum[blockIdx.x] = s[255];
}

// scanC with inline exclusive block-offset: each block reduces bsum[0..blockIdx-1] itself.
__global__ void k_scanC(const int* __restrict__ deg, int* __restrict__ rowptr,
                        const int* __restrict__ bsum, int nb) {
    __shared__ int s[256];
    int tid = threadIdx.x;
    s[tid] = (tid < nb && tid < blockIdx.x) ? bsum[tid] : 0;
    __syncthreads();
    for (int off = 128; off; off >>= 1) {
        if (tid < off) s[tid] += s[tid + off];
        __syncthreads();
    }
    int blockoff = s[0];
    int i = blockIdx.x * 256 + tid;
    if (i >= N_NODES) return;
    rowptr[i] = blockoff + rowptr[i] - deg[i];              // exclusive global
    if (i == N_NODES - 1) rowptr[N_NODES] = E_TOTAL;
}

// ---------------- merged: atomic-free CSR fill  +  layer-1 feature GEMM ----------------
#define FG_FILL 3321          // NB_E blocks for fill
#define FG_GEMM 3125          // N/16 blocks for gemm
__device__ __forceinline__ void gemm_feat_body(int bid, const ushort* __restrict__ x,
                                               const ushort* __restrict__ WbfT,
                                               const float* __restrict__ al, const float* __restrict__ ar,
                                               ushort* __restrict__ featB,
                                               float* __restrict__ el, float* __restrict__ er,
                                               float (*fs)[256]) {
    int tid = threadIdx.x;
    int wave = tid >> 6, lane = tid & 63;
    int row0 = bid * 16;
    int lr = lane & 15;      // A row / B col within tile
    int q = lane >> 4;       // k-chunk (8 k's per chunk)

    // A fragments: two 16B vector loads (all 4 waves same 16 rows; L1-hit)
    const ushort* ap = x + (size_t)(row0 + lr) * 64 + q * 8;
    bf16x8 a0 = *reinterpret_cast<const bf16x8*>(ap);
    bf16x8 a1 = *reinterpret_cast<const bf16x8*>(ap + 32);

#pragma unroll
    for (int t = 0; t < 4; t++) {
        int ct = wave * 4 + t;
        const ushort* wrow = WbfT + (size_t)(ct * 16 + lr) * 64 + q * 8;
        bf16x8 b0 = *reinterpret_cast<const bf16x8*>(wrow);        // k 0..31 chunk
        bf16x8 b1 = *reinterpret_cast<const bf16x8*>(wrow + 32);   // k 32..63 chunk
        f32x4 acc = {0.f, 0.f, 0.f, 0.f};
        acc = __builtin_amdgcn_mfma_f32_16x16x32_bf16(a0, b0, acc, 0, 0, 0);
        acc = __builtin_amdgcn_mfma_f32_16x16x32_bf16(a1, b1, acc, 0, 0, 0);
#pragma unroll
        for (int i = 0; i < 4; i++)
            fs[q * 4 + i][ct * 16 + lr] = acc[i];
    }
    __syncthreads();

    // el/er: task (r,h) over 4 lanes, each lane sums 16 dims
    {
        int r = tid >> 4;
        int rem = tid & 15;
        int h = rem >> 2;
        int l = rem & 3;
        int d0 = l * 16;
        float vl = 0.f, vr = 0.f;
#pragma unroll
        for (int j = 0; j < 16; j += 4) {
            float4 f = *(const float4*)&fs[r][h * 64 + d0 + j];
            float4 a = *(const float4*)&al[h * 64 + d0 + j];
            float4 b = *(const float4*)&ar[h * 64 + d0 + j];
            vl += f.x * a.x + f.y * a.y + f.z * a.z + f.w * a.w;
            vr += f.x * b.x + f.y * b.y + f.z * b.z + f.w * b.w;
        }
        vl += __shfl_xor(vl, 1, 64); vl += __shfl_xor(vl, 2, 64);
        vr += __shfl_xor(vr, 1, 64); vr += __shfl_xor(vr, 2, 64);
        if (l == 0) {
            el[(row0 + r) * 4 + h] = vl;
            er[(row0 + r) * 4 + h] = vr;
        }
    }

    // featB[i*256 + j], j=d*4+h -> source col = (j&3)*64 + (j>>2)
    int c = tid;
    int srcc = ((c & 3) << 6) + (c >> 2);
#pragma unroll
    for (int r = 0; r < 16; r++)
        featB[(size_t)(row0 + r) * 256 + c] = f2bf(fs[r][srcc]);
}

__global__ void k_fill_gemm(const int* __restrict__ ei, const int* __restrict__ rowptr,
                            const ushort* __restrict__ rank, ushort* __restrict__ colidx,
                            const ushort* __restrict__ x, const ushort* __restrict__ WbfT,
                            const float* __restrict__ al, const float* __restrict__ ar,
                            ushort* __restrict__ featB, float* __restrict__ el, float* __restrict__ er) {
    __shared__ float fs[16][256];
    if (blockIdx.x < FG_FILL) {
        int e = blockIdx.x * 256 + threadIdx.x;
        if (e >= E_TOTAL) return;
        int src, dst;
        if (e < E0_EDGES) { src = ei[e]; dst = ei[E0_EDGES + e]; }
        else { src = e - E0_EDGES; dst = src; }
        colidx[rowptr[dst] + rank[e]] = (ushort)src;
        return;
    }
    gemm_feat_body(blockIdx.x - FG_FILL, x, WbfT, al, ar, featB, el, er, fs);
}

__global__ void k_gemm_feat(const ushort* __restrict__ x, const ushort* __restrict__ WbfT,
                            const float* __restrict__ al, const float* __restrict__ ar,
                            ushort* __restrict__ featB, float* __restrict__ el, float* __restrict__ er) {
    __shared__ float fs[16][256];
    gemm_feat_body(blockIdx.x, x, WbfT, al, ar, featB, el, er, fs);
}

// ---------------- merged edge-softmax + aggregation (R7 proven form) ----------------
// Max pass removed (softmax shift-invariance; |logit| <= ~1 so no overflow).
__global__ void k_gat(const float4* __restrict__ el4, const float4* __restrict__ er4,
                      const int* __restrict__ rowptr, const ushort* __restrict__ colidx,
                      const ushort* __restrict__ featB, const float* __restrict__ bias,
                      ushort* __restrict__ hout) {
    __shared__ float4 sE[4][CAP];
    __shared__ int    sSrc[4][CAP];
    int tid = threadIdx.x;
    int w = tid >> 6, lane = tid & 63;
    int row = blockIdx.x * 4 + w;
    int start = rowptr[row];
    int deg = rowptr[row + 1] - start;
    int cached = min(deg, CAP);
    float4 erow = er4[row];

    // phase 1: logits -> exp -> LDS cache + denom
    float4 sm = make_float4(0.f, 0.f, 0.f, 0.f);
    for (int idx = lane; idx < cached; idx += 64) {
        int src = colidx[start + idx];
        float4 e = el4[src];
        float4 ex;
        ex.x = __expf(lrelu(e.x + erow.x));
        ex.y = __expf(lrelu(e.y + erow.y));
        ex.z = __expf(lrelu(e.z + erow.z));
        ex.w = __expf(lrelu(e.w + erow.w));
        sE[w][idx] = ex; sSrc[w][idx] = src;
        sm.x += ex.x; sm.y += ex.y; sm.z += ex.z; sm.w += ex.w;
    }
    for (int idx = CAP + lane; idx < deg; idx += 64) {      // rare tail
        int src = colidx[start + idx];
        float4 e = el4[src];
        sm.x += __expf(lrelu(e.x + erow.x));
        sm.y += __expf(lrelu(e.y + erow.y));
        sm.z += __expf(lrelu(e.z + erow.z));
        sm.w += __expf(lrelu(e.w + erow.w));
    }
#pragma unroll
    for (int off = 32; off; off >>= 1) {
        sm.x += __shfl_xor(sm.x, off, 64);
        sm.y += __shfl_xor(sm.y, off, 64);
        sm.z += __shfl_xor(sm.z, off, 64);
        sm.w += __shfl_xor(sm.w, off, 64);
    }
    float4 dr;
    dr.x = 1.f / sm.x; dr.y = 1.f / sm.y; dr.z = 1.f / sm.z; dr.w = 1.f / sm.w;

    // phase 2: serial edge loop, lane = dim; unroll 4 (VGPR/occ sweet spot)
    const ushort4* featB4 = (const ushort4*)featB;
    float4 acc = make_float4(0.f, 0.f, 0.f, 0.f);
#pragma unroll 4
    for (int s = 0; s < cached; s++) {
        float4 ex = sE[w][s];
        int src = sSrc[w][s];
        ushort4 f = featB4[(size_t)src * 64 + lane];
        acc.x = fmaf(bf2f(f.x), ex.x, acc.x);
        acc.y = fmaf(bf2f(f.y), ex.y, acc.y);
        acc.z = fmaf(bf2f(f.z), ex.z, acc.z);
        acc.w = fmaf(bf2f(f.w), ex.w, acc.w);
    }
    for (int s = CAP; s < deg; s++) {                       // rare tail
        int src = colidx[start + s];
        float4 e = el4[src];
        float4 ex;
        ex.x = __expf(lrelu(e.x + erow.x));
        ex.y = __expf(lrelu(e.y + erow.y));
        ex.z = __expf(lrelu(e.z + erow.z));
        ex.w = __expf(lrelu(e.w + erow.w));
        ushort4 f = featB4[(size_t)src * 64 + lane];
        acc.x = fmaf(bf2f(f.x), ex.x, acc.x);
        acc.y = fmaf(bf2f(f.y), ex.y, acc.y);
        acc.z = fmaf(bf2f(f.z), ex.z, acc.z);
        acc.w = fmaf(bf2f(f.w), ex.w, acc.w);
    }
    float o = fmaxf(fmaf(acc.x, dr.x, bias[lane]), 0.f)
            + fmaxf(fmaf(acc.y, dr.y, bias[64 + lane]), 0.f)
            + fmaxf(fmaf(acc.z, dr.z, bias[128 + lane]), 0.f)
            + fmaxf(fmaf(acc.w, dr.w, bias[192 + lane]), 0.f);
    hout[(size_t)row * 64 + lane] = f2bf(o * 0.25f);
}

// ---------------- MLP layer-1 via MFMA, atomic-light stats ----------------
// 128 rows/block (4 chunks of 32), 8 waves. Stats accumulated in REGISTERS across
// chunks, shfl-reduced over q once, LDS-combined across wave-halves, then ONE
// atomic pair per column per block -> 391 RMW/address (was 3126: the 120us chain).
#define MLP_TILES 13
#define MLP_RPB 128
__global__ __launch_bounds__(512) void k_mlp1_mfma(const ushort* __restrict__ h, const ushort* __restrict__ mwT,
                                                   const float* __restrict__ mb1, ushort* __restrict__ z,
                                                   float* __restrict__ gsum, float* __restrict__ gsumsq) {
    __shared__ float sS[2][208], sS2[2][208];
    int tid = threadIdx.x;
    int wave = tid >> 6, lane = tid & 63;
    int lr = lane & 15, q = lane >> 4;
    int half = wave >> 2;                       // 16-row subtile within chunk
    int tidx = wave & 3;                        // col-tile stride offset

    float sreg[4] = {0.f, 0.f, 0.f, 0.f};
    float s2reg[4] = {0.f, 0.f, 0.f, 0.f};

    for (int chunk = 0; chunk < 4; chunk++) {
        int rowbase = blockIdx.x * MLP_RPB + chunk * 32 + half * 16;
        const ushort* ap = h + (size_t)(rowbase + lr) * 64 + q * 8;
        bf16x8 a0 = *reinterpret_cast<const bf16x8*>(ap);
        bf16x8 a1 = *reinterpret_cast<const bf16x8*>(ap + 32);
        int t = 0;
        for (int ct = tidx; ct < MLP_TILES; ct += 4, t++) {
            const ushort* wrow = mwT + (size_t)(ct * 16 + lr) * 64 + q * 8;
            bf16x8 b0 = *reinterpret_cast<const bf16x8*>(wrow);
            bf16x8 b1 = *reinterpret_cast<const bf16x8*>(wrow + 32);
            f32x4 acc = {0.f, 0.f, 0.f, 0.f};
            acc = __builtin_amdgcn_mfma_f32_16x16x32_bf16(a0, b0, acc, 0, 0, 0);
            acc = __builtin_amdgcn_mfma_f32_16x16x32_bf16(a1, b1, acc, 0, 0, 0);

            int col = ct * 16 + lr;
            bool colok = (col < 200);
            float bv = colok ? mb1[col] : 0.f;
#pragma unroll
            for (int i = 0; i < 4; i++) {
                int row = rowbase + q * 4 + i;
                float v = fmaxf(acc[i] + bv, 0.f);
                if (colok && row < N_NODES) {
                    z[(size_t)row * 200 + col] = f2bf(v);
                    sreg[t] += v;
                    s2reg[t] = fmaf(v, v, s2reg[t]);
                }
            }
        }
    }

    // one shfl reduce over q per tile; unique (half,col) writer into LDS
    {
        int t = 0;
        for (int ct = tidx; ct < MLP_TILES; ct += 4, t++) {
            float s = sreg[t], s2 = s2reg[t];
            s  += __shfl_xor(s, 16, 64);  s  += __shfl_xor(s, 32, 64);
            s2 += __shfl_xor(s2, 16, 64); s2 += __shfl_xor(s2, 32, 64);
            if (q == 0) {
                int col = ct * 16 + lr;
                sS[half][col] = s;
                sS2[half][col] = s2;
            }
        }
    }
    __syncthreads();
    if (tid < 200) {
        atomicAdd(&gsum[tid], sS[0][tid] + sS[1][tid]);
        atomicAdd(&gsumsq[tid], sS2[0][tid] + sS2[1][tid]);
    }
}

// ---------------- final linear with BN folded in-kernel ----------------
__global__ void k_final(const ushort* __restrict__ z, const float* __restrict__ gsum,
                        const float* __restrict__ gsumsq, const float* __restrict__ bn_g,
                        const float* __restrict__ bn_b, const float* __restrict__ mw2,
                        const float* __restrict__ mb2, float* __restrict__ out) {
    int tid = threadIdx.x;
    int row = blockIdx.x * 4 + (tid >> 6);
    int lane = tid & 63;
    const float invN = 1.f / (float)N_NODES;
    float a0 = 0.f, a1 = 0.f;
    for (int c = lane; c < 200; c += 64) {
        float mu = gsum[c] * invN;
        float var = gsumsq[c] * invN - mu * mu;
        float alpha = bn_g[c] * rsqrtf(var + BN_EPS);
        float beta = bn_b[c] - mu * alpha;
        float zn = fmaf(alpha, bf2f(z[(size_t)row * 200 + c]), beta);
        a0 = fmaf(zn, mw2[c * 2], a0);
        a1 = fmaf(zn, mw2[c * 2 + 1], a1);
    }
#pragma unroll
    for (int off = 32; off; off >>= 1) {
        a0 += __shfl_xor(a0, off, 64);
        a1 += __shfl_xor(a1, off, 64);
    }
    if (lane == 0) {
        out[row * 2] = a0 + mb2[0];
        out[row * 2 + 1] = a1 + mb2[1];
    }
}

extern "C" void kernel_launch(void* const* d_in, const int* in_sizes, int n_in,
                              void* d_out, int out_size, void* d_ws, size_t ws_size,
                              hipStream_t stream) {
    const float* features = (const float*)d_in[0];
    const int*   ei       = (const int*)d_in[1];
    const float* W1  = (const float*)d_in[2];
    const float* al1 = (const float*)d_in[3];
    const float* ar1 = (const float*)d_in[4];
    const float* b1  = (const float*)d_in[5];
    const float* W2  = (const float*)d_in[6];
    const float* al2 = (const float*)d_in[7];
    const float* ar2 = (const float*)d_in[8];
    const float* b2  = (const float*)d_in[9];
    const float* mw1 = (const float*)d_in[10];
    const float* mb1 = (const float*)d_in[11];
    const float* bng = (const float*)d_in[12];
    const float* bnb = (const float*)d_in[13];
    const float* mw2 = (const float*)d_in[14];
    const float* mb2 = (const float*)d_in[15];
    float* out = (float*)d_out;

    // ---- workspace layout ----
    char* base = (char*)d_ws;
    size_t off = 0;
    auto alloc = [&](size_t bytes) -> char* {
        char* p = base + off;
        off = (off + bytes + 255) & ~(size_t)255;
        return p;
    };
    int*    deg    = (int*)alloc(N_NODES * 4);
    int*    rowptr = (int*)alloc((N_NODES + 1) * 4);
    ushort* rank   = (ushort*)alloc(E_TOTAL * 2);
    int*    bsum   = (int*)alloc(256 * 4);
    ushort* colidx = (ushort*)alloc(E_TOTAL * 2);
    ushort* featB  = (ushort*)alloc((size_t)N_NODES * 256 * 2);
    float*  el     = (float*)alloc((size_t)N_NODES * 4 * 4);
    float*  er     = (float*)alloc((size_t)N_NODES * 4 * 4);
    ushort* xbf    = (ushort*)alloc((size_t)N_NODES * 64 * 2);
    ushort* h1     = (ushort*)alloc((size_t)N_NODES * 64 * 2);
    ushort* h2     = (ushort*)alloc((size_t)N_NODES * 64 * 2);
    ushort* z      = (ushort*)alloc((size_t)N_NODES * 200 * 2);
    float*  gsum   = (float*)alloc(256 * 4);
    float*  gsumsq = (float*)alloc(256 * 4);
    ushort* WbfT1  = (ushort*)alloc(256 * 64 * 2);
    ushort* WbfT2  = (ushort*)alloc(256 * 64 * 2);
    ushort* mwT    = (ushort*)alloc(208 * 64 * 2);
    (void)ws_size; (void)in_sizes; (void)n_in; (void)out_size;

    const int NB_N = (N_NODES + 255) / 256;   // 196
    const int NB_E = (E_TOTAL + 255) / 256;   // 3321

    // prep + CSR build
    k_prep<<<PREP_Z + PREP_W + PREP_F, 256, 0, stream>>>(deg, gsum, gsumsq,
                                                         W1, W2, WbfT1, WbfT2,
                                                         mw1, mwT, features, xbf);
    k_count<<<NB_E, 256, 0, stream>>>(ei, deg, rank);
    k_scanA<<<NB_N, 256, 0, stream>>>(deg, rowptr, bsum);
    k_scanC<<<NB_N, 256, 0, stream>>>(deg, rowptr, bsum, NB_N);

    // GAT layer 1 (fill + gemm fused)
    k_fill_gemm<<<FG_FILL + FG_GEMM, 256, 0, stream>>>(ei, rowptr, rank, colidx,
                                                       xbf, WbfT1, al1, ar1, featB, el, er);
    k_gat<<<N_NODES / 4, 256, 0, stream>>>((const float4*)el, (const float4*)er, rowptr, colidx, featB, b1, h1);

    // GAT layer 2
    k_gemm_feat<<<N_NODES / 16, 256, 0, stream>>>(h1, WbfT2, al2, ar2, featB, el, er);
    k_gat<<<N_NODES / 4, 256, 0, stream>>>((const float4*)el, (const float4*)er, rowptr, colidx, featB, b2, h2);

    // MLP head (MFMA GEMM + atomic-light stats; BN folded into final)
    k_mlp1_mfma<<<(N_NODES + MLP_RPB - 1) / MLP_RPB, 512, 0, stream>>>(h2, mwT, mb1, z, gsum, gsumsq);
    k_final<<<N_NODES / 4, 256, 0, stream>>>(z, gsum, gsumsq, bng, bnb, mw2, mb2, out);
}